// Round 6
// baseline (383.254 us; speedup 1.0000x reference)
//
#include <hip/hip_runtime.h>
#include <hip/hip_cooperative_groups.h>

#define N_NODES 100000
#define D 128
#define N_EDGES 1600000
#define NBINS 3125          // fine bins: 32 nodes each
#define BCAP 1024           // fine bin cap (mean 512)
#define NCB 49              // coarse bins: 2048 nodes each (dst >> 11)
#define CCAP 40960          // coarse bin cap (mean ~32.7K)
#define EPB1 1000           // edges per coarse chunk
#define NCBLK 1600          // coarse chunks
#define NFBLK 2048          // fallback conv blocks
#define SLICE 2048          // fine-bin slice
#define NSLICE 20           // CCAP / SLICE
#define AST 136
#define LCAP 64
#define LST 68
#define NV   ((N_NODES * D) / 8)    // 1,600,000 feat vec8 items
#define NWV  (16384 / 8)            // 2,048 W vec8 items
#define NCONV (NV + NWV)
#define NCONV_HALF (NCONV / 2)

typedef unsigned short u16;
typedef __attribute__((ext_vector_type(8))) short short8;
typedef __attribute__((ext_vector_type(8))) unsigned short ushort8;
typedef __attribute__((ext_vector_type(4))) float f32x4;

__device__ __forceinline__ u16 f2bf(float f) {
    union { float f; unsigned int i; } c;
    c.f = f;
    unsigned int r = c.i + 0x7FFFu + ((c.i >> 16) & 1u);
    return (u16)(r >> 16);
}

__device__ __forceinline__ void bf16_acc8(unsigned int u, float* a) {
    union { unsigned int i; float f; } c;
    c.i = u << 16;          a[0] += c.f;
    c.i = u & 0xffff0000u;  a[1] += c.f;
}

// ---------------- shared-memory overlays ----------------
struct ShC { int2 stash[EPB1]; int hist[NCB]; int hbase[NCB]; };                       // 8.4 KB
struct ShF { unsigned stash[SLICE]; unsigned char fwb[SLICE]; int hist[64]; int hbase[64]; }; // 10.8 KB
struct ShG { u16 Al[32 * AST]; int lists[32 * LST]; int lcnt[32]; };                    // 17.5 KB
union ShU { ShC c; ShF f; ShG g; };

// ---------------- device bodies ----------------
__device__ __forceinline__ void conv_item(int i, const float* __restrict__ feat,
                                          const float* __restrict__ Wg,
                                          u16* __restrict__ featb, u16* __restrict__ Wbf) {
    const float* src;
    u16* dst;
    if (i < NV) { int idx = i * 8; src = feat + idx; dst = featb + idx; }
    else        { int idx = (i - NV) * 8; src = Wg + idx; dst = Wbf + idx; }
    f32x4 v0 = *(const f32x4*)(src);
    f32x4 v1 = *(const f32x4*)(src + 4);
    ushort8 o;
    o[0] = f2bf(v0.x); o[1] = f2bf(v0.y); o[2] = f2bf(v0.z); o[3] = f2bf(v0.w);
    o[4] = f2bf(v1.x); o[5] = f2bf(v1.y); o[6] = f2bf(v1.z); o[7] = f2bf(v1.w);
    *(ushort8*)dst = o;
}

__device__ void coarse_chunk(int ch, const int* __restrict__ esrc, const int* __restrict__ edst,
                             int* __restrict__ gcnt, int2* __restrict__ cpool, ShC* S) {
    const int t = threadIdx.x;
    const int base = ch * EPB1;
    if (t < NCB) S->hist[t] = 0;
    __syncthreads();
    for (int i = t; i < EPB1; i += 256) {
        int s = esrc[base + i];
        int d0 = edst[base + i];
        S->stash[i] = make_int2(s, d0);
        atomicAdd(&S->hist[d0 >> 11], 1);
    }
    __syncthreads();
    if (t < NCB) {
        int h = S->hist[t];
        S->hbase[t] = h ? atomicAdd(gcnt + 3136 + t, h) : 0;
        S->hist[t] = 0;
    }
    __syncthreads();
    for (int i = t; i < EPB1; i += 256) {
        int2 p = S->stash[i];
        int c = p.y >> 11;
        int r = atomicAdd(&S->hist[c], 1);
        int pos = S->hbase[c] + r;
        if (pos < CCAP) cpool[c * CCAP + pos] = p;
    }
    __syncthreads();   // protect hist before next chunk reuse
}

__device__ void fine_slice(int sb, int* __restrict__ gcnt, const int2* __restrict__ cpool,
                           unsigned* __restrict__ pool, ShF* S) {
    const int t = threadIdx.x;
    const int cb = sb / NSLICE;
    const int sl = sb % NSLICE;
    int cnt = gcnt[3136 + cb];
    if (cnt > CCAP) cnt = CCAP;
    int ne = cnt - sl * SLICE;
    if (ne <= 0) return;                     // uniform (cnt,sl uniform per block)
    if (ne > SLICE) ne = SLICE;

    if (t < 64) S->hist[t] = 0;
    __syncthreads();
    const int2* seg = cpool + cb * CCAP + sl * SLICE;
    for (int i = t; i < ne; i += 256) {
        int2 p = seg[i];
        unsigned fw = ((unsigned)p.y >> 5) & 63u;
        S->stash[i] = ((unsigned)(p.y & 31) << 17) | (unsigned)p.x;
        S->fwb[i] = (unsigned char)fw;
        atomicAdd(&S->hist[fw], 1);
    }
    __syncthreads();
    if (t < 64) {
        int h = S->hist[t];
        S->hbase[t] = h ? atomicAdd(gcnt + cb * 64 + t, h) : 0;
        S->hist[t] = 0;
    }
    __syncthreads();
    for (int i = t; i < ne; i += 256) {
        int fw = S->fwb[i];
        int r = atomicAdd(&S->hist[fw], 1);
        int pos = S->hbase[fw] + r;
        if (pos < BCAP) pool[(size_t)(cb * 64 + fw) * BCAP + pos] = S->stash[i];
    }
    __syncthreads();   // protect hist before next slice reuse
}

__device__ void fused_bin(int bin, const u16* __restrict__ fb, const int* __restrict__ gcnt,
                          const unsigned* __restrict__ pool, const u16* __restrict__ Wbf,
                          const float* __restrict__ bg, float* __restrict__ out, ShG* S) {
    const int t = threadIdx.x;
    const int nbase = bin * 32;
    const int nl = t >> 3;
    const int g = t & 7;
    const int n = nbase + nl;

    __syncthreads();   // protect LDS reuse across consecutive bins / phases

    // ---- phase 0: scan own fine-bin segment, build LDS lists ----
    {
        int ne = gcnt[bin];
        if (ne > BCAP) ne = BCAP;
        if (t < 32) S->lcnt[t] = 0;
        __syncthreads();
        const unsigned* seg = pool + (size_t)bin * BCAP;
        for (int i = t; i < ne; i += 256) {
            unsigned p = seg[i];
            unsigned rel = p >> 17;                  // < 32
            int r = atomicAdd(&S->lcnt[rel], 1);
            if (r < LCAP) S->lists[rel * LST + r] = (int)(p & 0x1FFFFu);
        }
        __syncthreads();
    }

    // ---- self row ----
    float acc[16];
    {
        const u16* fr = fb + (size_t)n * D + g * 16;
        uint4 p0 = *(const uint4*)(fr);
        uint4 p1 = *(const uint4*)(fr + 8);
        #pragma unroll
        for (int k = 0; k < 16; k++) acc[k] = 0.f;
        bf16_acc8(p0.x, acc + 0);  bf16_acc8(p0.y, acc + 2);
        bf16_acc8(p0.z, acc + 4);  bf16_acc8(p0.w, acc + 6);
        bf16_acc8(p1.x, acc + 8);  bf16_acc8(p1.y, acc + 10);
        bf16_acc8(p1.z, acc + 12); bf16_acc8(p1.w, acc + 14);
    }

    // ---- neighbor gather (4-wide, simple — the measured-best form) ----
    int deg = S->lcnt[nl];
    if (deg > LCAP) deg = LCAP;
    const int* bk = S->lists + nl * LST;
    int e = 0;
    for (; e + 4 <= deg; e += 4) {
        int4 s4 = *(const int4*)(bk + e);
        const u16* r0 = fb + (size_t)s4.x * D + g * 16;
        const u16* r1 = fb + (size_t)s4.y * D + g * 16;
        const u16* r2 = fb + (size_t)s4.z * D + g * 16;
        const u16* r3 = fb + (size_t)s4.w * D + g * 16;
        uint4 a0 = *(const uint4*)(r0), b0 = *(const uint4*)(r0 + 8);
        uint4 a1 = *(const uint4*)(r1), b1 = *(const uint4*)(r1 + 8);
        uint4 a2 = *(const uint4*)(r2), b2 = *(const uint4*)(r2 + 8);
        uint4 a3 = *(const uint4*)(r3), b3 = *(const uint4*)(r3 + 8);
        bf16_acc8(a0.x, acc+0); bf16_acc8(a0.y, acc+2); bf16_acc8(a0.z, acc+4); bf16_acc8(a0.w, acc+6);
        bf16_acc8(b0.x, acc+8); bf16_acc8(b0.y, acc+10); bf16_acc8(b0.z, acc+12); bf16_acc8(b0.w, acc+14);
        bf16_acc8(a1.x, acc+0); bf16_acc8(a1.y, acc+2); bf16_acc8(a1.z, acc+4); bf16_acc8(a1.w, acc+6);
        bf16_acc8(b1.x, acc+8); bf16_acc8(b1.y, acc+10); bf16_acc8(b1.z, acc+12); bf16_acc8(b1.w, acc+14);
        bf16_acc8(a2.x, acc+0); bf16_acc8(a2.y, acc+2); bf16_acc8(a2.z, acc+4); bf16_acc8(a2.w, acc+6);
        bf16_acc8(b2.x, acc+8); bf16_acc8(b2.y, acc+10); bf16_acc8(b2.z, acc+12); bf16_acc8(b2.w, acc+14);
        bf16_acc8(a3.x, acc+0); bf16_acc8(a3.y, acc+2); bf16_acc8(a3.z, acc+4); bf16_acc8(a3.w, acc+6);
        bf16_acc8(b3.x, acc+8); bf16_acc8(b3.y, acc+10); bf16_acc8(b3.z, acc+12); bf16_acc8(b3.w, acc+14);
    }
    for (; e < deg; e++) {
        const u16* r0 = fb + (size_t)bk[e] * D + g * 16;
        uint4 a0 = *(const uint4*)(r0), b0 = *(const uint4*)(r0 + 8);
        bf16_acc8(a0.x, acc+0); bf16_acc8(a0.y, acc+2); bf16_acc8(a0.z, acc+4); bf16_acc8(a0.w, acc+6);
        bf16_acc8(b0.x, acc+8); bf16_acc8(b0.y, acc+10); bf16_acc8(b0.z, acc+12); bf16_acc8(b0.w, acc+14);
    }

    // ---- normalize ----
    float ss = 0.f;
    #pragma unroll
    for (int k = 0; k < 16; k++) ss += acc[k] * acc[k];
    #pragma unroll
    for (int off = 4; off; off >>= 1) ss += __shfl_xor(ss, off, 8);
    const float inv = 1.0f / fmaxf(sqrtf(ss), 1e-12f);

    {
        ushort8 o0, o1;
        o0[0]=f2bf(acc[0]*inv); o0[1]=f2bf(acc[1]*inv); o0[2]=f2bf(acc[2]*inv); o0[3]=f2bf(acc[3]*inv);
        o0[4]=f2bf(acc[4]*inv); o0[5]=f2bf(acc[5]*inv); o0[6]=f2bf(acc[6]*inv); o0[7]=f2bf(acc[7]*inv);
        o1[0]=f2bf(acc[8]*inv); o1[1]=f2bf(acc[9]*inv); o1[2]=f2bf(acc[10]*inv); o1[3]=f2bf(acc[11]*inv);
        o1[4]=f2bf(acc[12]*inv); o1[5]=f2bf(acc[13]*inv); o1[6]=f2bf(acc[14]*inv); o1[7]=f2bf(acc[15]*inv);
        u16* dst = S->Al + nl * AST + g * 16;
        *(ushort8*)(dst)     = o0;
        *(ushort8*)(dst + 8) = o1;
    }
    __syncthreads();

    // ---- MFMA GEMM: [32x128] x [128x128]^T ----
    const int w = t >> 6, lane = t & 63;
    const int mb = (w >> 1) * 16, nb = (w & 1) * 64;
    const int quad = lane >> 4, r = lane & 15;
    f32x4 c0 = {0,0,0,0}, c1 = {0,0,0,0}, c2 = {0,0,0,0}, c3 = {0,0,0,0};
    #pragma unroll
    for (int kt = 0; kt < 4; kt++) {
        const int ko = kt * 32 + quad * 8;
        short8 a  = *(const short8*)(S->Al + (mb + r) * AST + ko);
        short8 b0 = *(const short8*)(Wbf + (nb +  0 + r) * D + ko);
        short8 b1 = *(const short8*)(Wbf + (nb + 16 + r) * D + ko);
        short8 b2 = *(const short8*)(Wbf + (nb + 32 + r) * D + ko);
        short8 b3 = *(const short8*)(Wbf + (nb + 48 + r) * D + ko);
        c0 = __builtin_amdgcn_mfma_f32_16x16x32_bf16(a, b0, c0, 0, 0, 0);
        c1 = __builtin_amdgcn_mfma_f32_16x16x32_bf16(a, b1, c1, 0, 0, 0);
        c2 = __builtin_amdgcn_mfma_f32_16x16x32_bf16(a, b2, c2, 0, 0, 0);
        c3 = __builtin_amdgcn_mfma_f32_16x16x32_bf16(a, b3, c3, 0, 0, 0);
    }
    {
        const float bb0 = bg[nb + r], bb1 = bg[nb + 16 + r];
        const float bb2 = bg[nb + 32 + r], bb3 = bg[nb + 48 + r];
        float* outb = out + (size_t)(nbase + mb + quad * 4) * D;
        #pragma unroll
        for (int reg = 0; reg < 4; reg++) {
            float* rowp = outb + reg * D + nb + r;
            rowp[0]  = c0[reg] + bb0;
            rowp[16] = c1[reg] + bb1;
            rowp[32] = c2[reg] + bb2;
            rowp[48] = c3[reg] + bb3;
        }
    }
}

// ---------------- cooperative mega-kernel ----------------
__global__ __launch_bounds__(256) void mega(const float* __restrict__ feat,
                                            const float* __restrict__ Wg,
                                            const int* __restrict__ esrc,
                                            const int* __restrict__ edst,
                                            u16* __restrict__ featb,
                                            u16* __restrict__ Wbf,
                                            int* __restrict__ gcnt,
                                            unsigned* __restrict__ pool,
                                            int2* __restrict__ cpool,
                                            const float* __restrict__ bg,
                                            float* __restrict__ out) {
    cooperative_groups::grid_group grid = cooperative_groups::this_grid();
    __shared__ ShU sh;
    const int t = threadIdx.x;
    const int nblk = gridDim.x;
    const int half = nblk >> 1;

    // ---- P0: coarse-bin (blocks [0,half)) || conv first half (blocks [half,nblk)) ----
    if ((int)blockIdx.x < half) {
        for (int ch = blockIdx.x; ch < NCBLK; ch += half)
            coarse_chunk(ch, esrc, edst, gcnt, cpool, &sh.c);
    } else {
        const int stride = (nblk - half) * 256;
        for (int i = ((int)blockIdx.x - half) * 256 + t; i < NCONV_HALF; i += stride)
            conv_item(i, feat, Wg, featb, Wbf);
    }
    grid.sync();

    // ---- P1: fine-bin (blocks [0,half)) || conv second half ----
    if ((int)blockIdx.x < half) {
        for (int sb = blockIdx.x; sb < NCB * NSLICE; sb += half)
            fine_slice(sb, gcnt, cpool, pool, &sh.f);
    } else {
        const int stride = (nblk - half) * 256;
        for (int i = NCONV_HALF + ((int)blockIdx.x - half) * 256 + t; i < NCONV; i += stride)
            conv_item(i, feat, Wg, featb, Wbf);
    }
    grid.sync();

    // ---- P2: fused gather + normalize + GEMM over all bins ----
    for (int bin = blockIdx.x; bin < NBINS; bin += nblk)
        fused_bin(bin, featb, gcnt, pool, Wbf, bg, out, &sh.g);
}

// ---------------- non-cooperative fallback (same bodies) ----------------
__global__ __launch_bounds__(256) void k_prep(const float* __restrict__ feat,
                                              const float* __restrict__ Wg,
                                              const int* __restrict__ esrc,
                                              const int* __restrict__ edst,
                                              u16* __restrict__ featb,
                                              u16* __restrict__ Wbf,
                                              int* __restrict__ gcnt,
                                              int2* __restrict__ cpool) {
    __shared__ ShU sh;
    const int b = blockIdx.x;
    if (b < NCBLK) {
        coarse_chunk(b, esrc, edst, gcnt, cpool, &sh.c);
    } else {
        for (int i = (b - NCBLK) * 256 + (int)threadIdx.x; i < NCONV; i += NFBLK * 256)
            conv_item(i, feat, Wg, featb, Wbf);
    }
}

__global__ __launch_bounds__(256) void k_fine(int* __restrict__ gcnt,
                                              const int2* __restrict__ cpool,
                                              unsigned* __restrict__ pool) {
    __shared__ ShU sh;
    fine_slice(blockIdx.x, gcnt, cpool, pool, &sh.f);
}

__global__ __launch_bounds__(256) void k_fused(const u16* __restrict__ fb,
                                               const int* __restrict__ gcnt,
                                               const unsigned* __restrict__ pool,
                                               const u16* __restrict__ Wbf,
                                               const float* __restrict__ bg,
                                               float* __restrict__ out) {
    __shared__ ShU sh;
    fused_bin(blockIdx.x, fb, gcnt, pool, Wbf, bg, out, &sh.g);
}

// ---------------- tiny-ws fallback push path ----------------
__global__ __launch_bounds__(256) void scatter(const float* __restrict__ feat,
                                               const int* __restrict__ esrc,
                                               const int* __restrict__ edst,
                                               float* __restrict__ agg) {
    int gid = blockIdx.x * 256 + threadIdx.x;
    int e = gid >> 5;
    int q = (gid & 31) << 2;
    int s = esrc[e];
    int d0 = edst[e];
    const float4 a = *(const float4*)(feat + s * D + q);
    float* dst = agg + d0 * D + q;
    unsafeAtomicAdd(dst + 0, a.x);
    unsafeAtomicAdd(dst + 1, a.y);
    unsafeAtomicAdd(dst + 2, a.z);
    unsafeAtomicAdd(dst + 3, a.w);
}

__global__ __launch_bounds__(256) void norm_linear_mfma(const float* __restrict__ Wg,
                                                        const float* __restrict__ bg,
                                                        float* __restrict__ out) {
    __shared__ u16 Wl[128 * AST];
    __shared__ u16 Al[32 * AST];
    __shared__ float bl[128];
    const int t = threadIdx.x;
    const int nbase = blockIdx.x * 32;

    for (int idx = t * 8; idx < 128 * 128; idx += 256 * 8) {
        int row = idx >> 7, col = idx & 127;
        f32x4 v0 = *(const f32x4*)(Wg + idx);
        f32x4 v1 = *(const f32x4*)(Wg + idx + 4);
        u16* dst = Wl + row * AST + col;
        dst[0] = f2bf(v0.x); dst[1] = f2bf(v0.y); dst[2] = f2bf(v0.z); dst[3] = f2bf(v0.w);
        dst[4] = f2bf(v1.x); dst[5] = f2bf(v1.y); dst[6] = f2bf(v1.z); dst[7] = f2bf(v1.w);
    }
    if (t < 128) bl[t] = bg[t];
    {
        const int n = t >> 3, seg = t & 7;
        const float* src = out + (nbase + n) * D + seg * 16;
        f32x4 v0 = *(const f32x4*)(src);
        f32x4 v1 = *(const f32x4*)(src + 4);
        f32x4 v2 = *(const f32x4*)(src + 8);
        f32x4 v3 = *(const f32x4*)(src + 12);
        float ss = v0.x*v0.x + v0.y*v0.y + v0.z*v0.z + v0.w*v0.w
                 + v1.x*v1.x + v1.y*v1.y + v1.z*v1.z + v1.w*v1.w
                 + v2.x*v2.x + v2.y*v2.y + v2.z*v2.z + v2.w*v2.w
                 + v3.x*v3.x + v3.y*v3.y + v3.z*v3.z + v3.w*v3.w;
        #pragma unroll
        for (int off = 4; off; off >>= 1) ss += __shfl_xor(ss, off, 8);
        const float inv = 1.0f / fmaxf(sqrtf(ss), 1e-12f);
        u16* dst = Al + n * AST + seg * 16;
        dst[0]  = f2bf(v0.x * inv); dst[1]  = f2bf(v0.y * inv);
        dst[2]  = f2bf(v0.z * inv); dst[3]  = f2bf(v0.w * inv);
        dst[4]  = f2bf(v1.x * inv); dst[5]  = f2bf(v1.y * inv);
        dst[6]  = f2bf(v1.z * inv); dst[7]  = f2bf(v1.w * inv);
        dst[8]  = f2bf(v2.x * inv); dst[9]  = f2bf(v2.y * inv);
        dst[10] = f2bf(v2.z * inv); dst[11] = f2bf(v2.w * inv);
        dst[12] = f2bf(v3.x * inv); dst[13] = f2bf(v3.y * inv);
        dst[14] = f2bf(v3.z * inv); dst[15] = f2bf(v3.w * inv);
    }
    __syncthreads();

    const int w = t >> 6, lane = t & 63;
    const int mb = (w >> 1) * 16, nb = (w & 1) * 64;
    const int quad = lane >> 4, r = lane & 15;
    f32x4 c0 = {0,0,0,0}, c1 = {0,0,0,0}, c2 = {0,0,0,0}, c3 = {0,0,0,0};
    #pragma unroll
    for (int kt = 0; kt < 4; kt++) {
        const int ko = kt * 32 + quad * 8;
        short8 a = *(const short8*)(Al + (mb + r) * AST + ko);
        short8 b0 = *(const short8*)(Wl + (nb +  0 + r) * AST + ko);
        short8 b1 = *(const short8*)(Wl + (nb + 16 + r) * AST + ko);
        short8 b2 = *(const short8*)(Wl + (nb + 32 + r) * AST + ko);
        short8 b3 = *(const short8*)(Wl + (nb + 48 + r) * AST + ko);
        c0 = __builtin_amdgcn_mfma_f32_16x16x32_bf16(a, b0, c0, 0, 0, 0);
        c1 = __builtin_amdgcn_mfma_f32_16x16x32_bf16(a, b1, c1, 0, 0, 0);
        c2 = __builtin_amdgcn_mfma_f32_16x16x32_bf16(a, b2, c2, 0, 0, 0);
        c3 = __builtin_amdgcn_mfma_f32_16x16x32_bf16(a, b3, c3, 0, 0, 0);
    }
    {
        float* outb = out + (nbase + mb + quad * 4) * D;
        const float bb0 = bl[nb + r], bb1 = bl[nb + 16 + r];
        const float bb2 = bl[nb + 32 + r], bb3 = bl[nb + 48 + r];
        #pragma unroll
        for (int reg = 0; reg < 4; reg++) {
            float* rowp = outb + reg * D + nb + r;
            rowp[0]  = c0[reg] + bb0;
            rowp[16] = c1[reg] + bb1;
            rowp[32] = c2[reg] + bb2;
            rowp[48] = c3[reg] + bb3;
        }
    }
}

extern "C" void kernel_launch(void* const* d_in, const int* in_sizes, int n_in,
                              void* d_out, int out_size, void* d_ws, size_t ws_size,
                              hipStream_t stream) {
    const float* feat = (const float*)d_in[0];
    const int*   esrc = (const int*)d_in[1];
    const int*   edst = (const int*)d_in[2];
    const float* W = (const float*)d_in[n_in - 2];
    const float* b = (const float*)d_in[n_in - 1];
    float* out = (float*)d_out;

    // ws layout (words): gcnt[3328] | Wbf[8192w] | fine pool[NBINS*BCAP] | featb[6400000w]
    // coarse pool (int2, NCB*CCAP = 2M = 16 MB) lives in d_out (overwritten by fused output).
    const long poolw = (long)NBINS * BCAP;
    const long need_bf16 = 3328 + 8192 + poolw + 6400000;
    const long availw = (long)(ws_size / 4);

    if (availw >= need_bf16) {
        int* gcnt = (int*)d_ws;
        u16* Wbf = (u16*)(gcnt + 3328);
        unsigned* pool = (unsigned*)(Wbf + 16384);
        u16* featb = (u16*)(pool + poolw);
        int2* cpool = (int2*)d_out;

        // one-time cooperative-launch capability + occupancy query (host-side, cached)
        static int coopBlocks = -2;
        if (coopBlocks == -2) {
            int coop = 0;
            if (hipDeviceGetAttribute(&coop, hipDeviceAttributeCooperativeLaunch, 0) != hipSuccess)
                coop = 0;
            if (coop) {
                int occ = 0, ncu = 0;
                if (hipOccupancyMaxActiveBlocksPerMultiprocessor(&occ, mega, 256, 0) != hipSuccess)
                    occ = 0;
                if (hipDeviceGetAttribute(&ncu, hipDeviceAttributeMultiprocessorCount, 0) != hipSuccess)
                    ncu = 0;
                coopBlocks = (occ > 0 && ncu > 0) ? (occ * ncu) & ~1 : -1;
                if (coopBlocks > 3124) coopBlocks = 3124;
                if (coopBlocks < 128) coopBlocks = -1;
            } else {
                coopBlocks = -1;
            }
        }

        hipMemsetAsync(gcnt, 0, 3328 * sizeof(int), stream);

        if (coopBlocks > 0) {
            void* args[] = { (void*)&feat, (void*)&W, (void*)&esrc, (void*)&edst,
                             (void*)&featb, (void*)&Wbf, (void*)&gcnt, (void*)&pool,
                             (void*)&cpool, (void*)&b, (void*)&out };
            hipError_t err = hipLaunchCooperativeKernel((const void*)mega, dim3(coopBlocks),
                                                        dim3(256), args, 0, stream);
            if (err == hipSuccess) return;
            coopBlocks = -1;   // remember failure, fall through
        }

        k_prep<<<NCBLK + NFBLK, 256, 0, stream>>>(feat, W, esrc, edst, featb, Wbf, gcnt, cpool);
        k_fine<<<NCB * NSLICE, 256, 0, stream>>>(gcnt, cpool, pool);
        k_fused<<<NBINS, 256, 0, stream>>>(featb, gcnt, pool, Wbf, b, out);
    } else {
        hipMemcpyAsync(out, feat, (size_t)N_NODES * D * sizeof(float),
                       hipMemcpyDeviceToDevice, stream);
        scatter<<<(N_EDGES * 32) / 256, 256, 0, stream>>>(feat, esrc, edst, out);
        norm_linear_mfma<<<N_NODES / 32, 256, 0, stream>>>(W, b, out);
    }
}

// Round 7
// 229.062 us; speedup vs baseline: 1.6731x; 1.6731x over previous
//
#include <hip/hip_runtime.h>

#define N_NODES 100000
#define D 128
#define N_EDGES 1600000
#define NBINS 3125          // fine bins: 32 nodes each, 1:1 with fused_gnl blocks
#define BCAP 1024           // fine bin cap (mean 512)
#define NCB 49              // coarse bins: 2048 nodes each (dst >> 11)
#define CCAP 40960          // coarse bin cap (mean ~32.7K)
#define EPB1 1000           // edges per coarse block
#define SLICE 2048          // fine-bin slice
#define NSLICE 20           // CCAP / SLICE
#define AST 136
#define LCAP 64
#define LST 68

typedef unsigned short u16;
typedef __attribute__((ext_vector_type(8))) short short8;
typedef __attribute__((ext_vector_type(8))) unsigned short ushort8;
typedef __attribute__((ext_vector_type(4))) float f32x4;

__device__ __forceinline__ u16 f2bf(float f) {
    union { float f; unsigned int i; } c;
    c.f = f;
    unsigned int r = c.i + 0x7FFFu + ((c.i >> 16) & 1u);
    return (u16)(r >> 16);
}

__device__ __forceinline__ void bf16_acc8(unsigned int u, float* a) {
    union { unsigned int i; float f; } c;
    c.i = u << 16;          a[0] += c.f;
    c.i = u & 0xffff0000u;  a[1] += c.f;
}

// ---------- conv_all: feat->bf16, W->bf16, zero gcnt ----------
// blocks [0,6250): feat conv; [6250,6258): W conv; [6258,6271): zero gcnt (3328 ints)
__global__ __launch_bounds__(256) void conv_all(const float* __restrict__ feat,
                                                const float* __restrict__ Wg,
                                                u16* __restrict__ featb,
                                                u16* __restrict__ Wbf,
                                                int* __restrict__ gcnt) {
    const int b = blockIdx.x, t = threadIdx.x;
    if (b < 6250) {
        if (!featb) return;
        int idx = (b * 256 + t) * 8;
        f32x4 v0 = *(const f32x4*)(feat + idx);
        f32x4 v1 = *(const f32x4*)(feat + idx + 4);
        ushort8 o;
        o[0] = f2bf(v0.x); o[1] = f2bf(v0.y); o[2] = f2bf(v0.z); o[3] = f2bf(v0.w);
        o[4] = f2bf(v1.x); o[5] = f2bf(v1.y); o[6] = f2bf(v1.z); o[7] = f2bf(v1.w);
        *(ushort8*)(featb + idx) = o;
    } else if (b < 6258) {
        int idx = ((b - 6250) * 256 + t) * 8;
        f32x4 v0 = *(const f32x4*)(Wg + idx);
        f32x4 v1 = *(const f32x4*)(Wg + idx + 4);
        ushort8 o;
        o[0] = f2bf(v0.x); o[1] = f2bf(v0.y); o[2] = f2bf(v0.z); o[3] = f2bf(v0.w);
        o[4] = f2bf(v1.x); o[5] = f2bf(v1.y); o[6] = f2bf(v1.z); o[7] = f2bf(v1.w);
        *(ushort8*)(Wbf + idx) = o;
    } else {
        int i = (b - 6258) * 256 + t;
        if (i < 3328) gcnt[i] = 0;
    }
}

// ---------- Pass 1: coarse bin with LDS counting-sort + linear (line-sized) flush ----------
// Coarse counters at gcnt+3136.
__global__ __launch_bounds__(256) void coarse_bin(const int* __restrict__ esrc,
                                                  const int* __restrict__ edst,
                                                  int* __restrict__ gcnt,
                                                  int2* __restrict__ cpool) {
    __shared__ int2 stash[EPB1];
    __shared__ int2 sorted[EPB1];
    __shared__ int hist[NCB];
    __shared__ int hbase[NCB];
    __shared__ int loff[NCB];
    const int t = threadIdx.x;
    const int base = blockIdx.x * EPB1;

    if (t < NCB) hist[t] = 0;
    __syncthreads();
    for (int i = t; i < EPB1; i += 256) {
        int s = esrc[base + i];
        int d0 = edst[base + i];
        stash[i] = make_int2(s, d0);
        atomicAdd(&hist[d0 >> 11], 1);
    }
    __syncthreads();
    if (t == 0) {                       // exclusive scan (49 elems, trivial)
        int run = 0;
        for (int c = 0; c < NCB; c++) { loff[c] = run; run += hist[c]; }
    }
    __syncthreads();
    if (t < NCB) {
        int h = hist[t];
        hbase[t] = h ? atomicAdd(gcnt + 3136 + t, h) : 0;
        hist[t] = 0;
    }
    __syncthreads();
    // rank + group by bin inside LDS
    for (int i = t; i < EPB1; i += 256) {
        int2 p = stash[i];
        int c = p.y >> 11;
        int r = atomicAdd(&hist[c], 1);
        sorted[loff[c] + r] = p;
    }
    __syncthreads();
    // linear flush: consecutive lanes -> consecutive global addresses
    for (int i = t; i < EPB1; i += 256) {
        int2 p = sorted[i];
        int c = p.y >> 11;
        int pos = hbase[c] + (i - loff[c]);
        if (pos < CCAP) cpool[c * CCAP + pos] = p;
    }
}

// ---------- Pass 2: fine bin with LDS counting-sort + linear flush ----------
// staged entry = fw<<22 | (dst&31)<<17 | src ; written entry strips fw.
__global__ __launch_bounds__(256) void fine_bin(int* __restrict__ gcnt,
                                                const int2* __restrict__ cpool,
                                                unsigned* __restrict__ pool) {
    __shared__ unsigned stash[SLICE];
    __shared__ unsigned sorted[SLICE];
    __shared__ int hist[64];
    __shared__ int hbase[64];
    __shared__ int loff[64];
    const int t = threadIdx.x;
    const int cb = blockIdx.x / NSLICE;
    const int sl = blockIdx.x % NSLICE;

    int cnt = gcnt[3136 + cb];
    if (cnt > CCAP) cnt = CCAP;
    int ne = cnt - sl * SLICE;
    if (ne <= 0) return;                 // uniform per block
    if (ne > SLICE) ne = SLICE;

    if (t < 64) hist[t] = 0;
    __syncthreads();
    const int2* seg = cpool + cb * CCAP + sl * SLICE;
    for (int i = t; i < ne; i += 256) {
        int2 p = seg[i];
        unsigned fw = ((unsigned)p.y >> 5) & 63u;
        stash[i] = (fw << 22) | ((unsigned)(p.y & 31) << 17) | (unsigned)p.x;
        atomicAdd(&hist[fw], 1);
    }
    __syncthreads();
    if (t == 0) {
        int run = 0;
        for (int c = 0; c < 64; c++) { loff[c] = run; run += hist[c]; }
    }
    __syncthreads();
    if (t < 64) {
        int h = hist[t];
        hbase[t] = h ? atomicAdd(gcnt + cb * 64 + t, h) : 0;
        hist[t] = 0;
    }
    __syncthreads();
    for (int i = t; i < ne; i += 256) {
        unsigned p = stash[i];
        unsigned fw = p >> 22;
        int r = atomicAdd(&hist[fw], 1);
        sorted[loff[fw] + r] = p;
    }
    __syncthreads();
    for (int i = t; i < ne; i += 256) {
        unsigned p = sorted[i];
        unsigned fw = p >> 22;
        int pos = hbase[fw] + (i - loff[fw]);
        if (pos < BCAP) pool[(size_t)(cb * 64 + fw) * BCAP + pos] = p & 0x3FFFFFu;
    }
}

// ---------- Fused: segment-scan -> LDS lists -> gather + normalize + GEMM (R4 body) ----------
template<bool BF16FEAT>
__global__ __launch_bounds__(256) void fused_gnl(const void* __restrict__ featv,
                                                 const int* __restrict__ gcnt,
                                                 const unsigned* __restrict__ pool,
                                                 const u16* __restrict__ Wbf,
                                                 const float* __restrict__ bg,
                                                 float* __restrict__ out) {
    __shared__ u16 Al[32 * AST];
    __shared__ int lists[32 * LST];
    __shared__ int lcnt[32];
    const int t = threadIdx.x;
    const int nbase = blockIdx.x * 32;
    const int nl = t >> 3;
    const int g = t & 7;
    const int n = nbase + nl;

    {
        int ne = gcnt[blockIdx.x];
        if (ne > BCAP) ne = BCAP;
        if (t < 32) lcnt[t] = 0;
        __syncthreads();
        const unsigned* seg = pool + (size_t)blockIdx.x * BCAP;
        for (int i = t; i < ne; i += 256) {
            unsigned p = seg[i];
            unsigned rel = p >> 17;                  // < 32
            int r = atomicAdd(&lcnt[rel], 1);
            if (r < LCAP) lists[rel * LST + r] = (int)(p & 0x1FFFFu);
        }
        __syncthreads();
    }

    float acc[16];
    if (BF16FEAT) {
        const u16* fb = (const u16*)featv + (size_t)n * D + g * 16;
        uint4 p0 = *(const uint4*)(fb);
        uint4 p1 = *(const uint4*)(fb + 8);
        #pragma unroll
        for (int k = 0; k < 16; k++) acc[k] = 0.f;
        bf16_acc8(p0.x, acc + 0);  bf16_acc8(p0.y, acc + 2);
        bf16_acc8(p0.z, acc + 4);  bf16_acc8(p0.w, acc + 6);
        bf16_acc8(p1.x, acc + 8);  bf16_acc8(p1.y, acc + 10);
        bf16_acc8(p1.z, acc + 12); bf16_acc8(p1.w, acc + 14);
    } else {
        const float* ff = (const float*)featv + (size_t)n * D + g * 16;
        f32x4 v0 = *(const f32x4*)(ff);
        f32x4 v1 = *(const f32x4*)(ff + 4);
        f32x4 v2 = *(const f32x4*)(ff + 8);
        f32x4 v3 = *(const f32x4*)(ff + 12);
        acc[0]=v0.x; acc[1]=v0.y; acc[2]=v0.z; acc[3]=v0.w;
        acc[4]=v1.x; acc[5]=v1.y; acc[6]=v1.z; acc[7]=v1.w;
        acc[8]=v2.x; acc[9]=v2.y; acc[10]=v2.z; acc[11]=v2.w;
        acc[12]=v3.x; acc[13]=v3.y; acc[14]=v3.z; acc[15]=v3.w;
    }

    int deg = lcnt[nl];
    if (deg > LCAP) deg = LCAP;
    const int* bk = lists + nl * LST;
    int e = 0;
    if (BF16FEAT) {
        const u16* fb = (const u16*)featv;
        for (; e + 4 <= deg; e += 4) {
            int4 s4 = *(const int4*)(bk + e);
            const u16* r0 = fb + (size_t)s4.x * D + g * 16;
            const u16* r1 = fb + (size_t)s4.y * D + g * 16;
            const u16* r2 = fb + (size_t)s4.z * D + g * 16;
            const u16* r3 = fb + (size_t)s4.w * D + g * 16;
            uint4 a0 = *(const uint4*)(r0), b0 = *(const uint4*)(r0 + 8);
            uint4 a1 = *(const uint4*)(r1), b1 = *(const uint4*)(r1 + 8);
            uint4 a2 = *(const uint4*)(r2), b2 = *(const uint4*)(r2 + 8);
            uint4 a3 = *(const uint4*)(r3), b3 = *(const uint4*)(r3 + 8);
            bf16_acc8(a0.x, acc+0); bf16_acc8(a0.y, acc+2); bf16_acc8(a0.z, acc+4); bf16_acc8(a0.w, acc+6);
            bf16_acc8(b0.x, acc+8); bf16_acc8(b0.y, acc+10); bf16_acc8(b0.z, acc+12); bf16_acc8(b0.w, acc+14);
            bf16_acc8(a1.x, acc+0); bf16_acc8(a1.y, acc+2); bf16_acc8(a1.z, acc+4); bf16_acc8(a1.w, acc+6);
            bf16_acc8(b1.x, acc+8); bf16_acc8(b1.y, acc+10); bf16_acc8(b1.z, acc+12); bf16_acc8(b1.w, acc+14);
            bf16_acc8(a2.x, acc+0); bf16_acc8(a2.y, acc+2); bf16_acc8(a2.z, acc+4); bf16_acc8(a2.w, acc+6);
            bf16_acc8(b2.x, acc+8); bf16_acc8(b2.y, acc+10); bf16_acc8(b2.z, acc+12); bf16_acc8(b2.w, acc+14);
            bf16_acc8(a3.x, acc+0); bf16_acc8(a3.y, acc+2); bf16_acc8(a3.z, acc+4); bf16_acc8(a3.w, acc+6);
            bf16_acc8(b3.x, acc+8); bf16_acc8(b3.y, acc+10); bf16_acc8(b3.z, acc+12); bf16_acc8(b3.w, acc+14);
        }
        for (; e < deg; e++) {
            const u16* r0 = fb + (size_t)bk[e] * D + g * 16;
            uint4 a0 = *(const uint4*)(r0), b0 = *(const uint4*)(r0 + 8);
            bf16_acc8(a0.x, acc+0); bf16_acc8(a0.y, acc+2); bf16_acc8(a0.z, acc+4); bf16_acc8(a0.w, acc+6);
            bf16_acc8(b0.x, acc+8); bf16_acc8(b0.y, acc+10); bf16_acc8(b0.z, acc+12); bf16_acc8(b0.w, acc+14);
        }
    } else {
        const float* ff = (const float*)featv;
        for (; e + 2 <= deg; e += 2) {
            int2 s2 = *(const int2*)(bk + e);
            const float* r0 = ff + (size_t)s2.x * D + g * 16;
            const float* r1 = ff + (size_t)s2.y * D + g * 16;
            f32x4 x0 = *(const f32x4*)(r0),     x1 = *(const f32x4*)(r0 + 4);
            f32x4 x2 = *(const f32x4*)(r0 + 8), x3 = *(const f32x4*)(r0 + 12);
            f32x4 y0 = *(const f32x4*)(r1),     y1 = *(const f32x4*)(r1 + 4);
            f32x4 y2 = *(const f32x4*)(r1 + 8), y3 = *(const f32x4*)(r1 + 12);
            acc[0]+=x0.x+y0.x; acc[1]+=x0.y+y0.y; acc[2]+=x0.z+y0.z; acc[3]+=x0.w+y0.w;
            acc[4]+=x1.x+y1.x; acc[5]+=x1.y+y1.y; acc[6]+=x1.z+y1.z; acc[7]+=x1.w+y1.w;
            acc[8]+=x2.x+y2.x; acc[9]+=x2.y+y2.y; acc[10]+=x2.z+y2.z; acc[11]+=x2.w+y2.w;
            acc[12]+=x3.x+y3.x; acc[13]+=x3.y+y3.y; acc[14]+=x3.z+y3.z; acc[15]+=x3.w+y3.w;
        }
        for (; e < deg; e++) {
            const float* r0 = ff + (size_t)bk[e] * D + g * 16;
            f32x4 x0 = *(const f32x4*)(r0),     x1 = *(const f32x4*)(r0 + 4);
            f32x4 x2 = *(const f32x4*)(r0 + 8), x3 = *(const f32x4*)(r0 + 12);
            acc[0]+=x0.x; acc[1]+=x0.y; acc[2]+=x0.z; acc[3]+=x0.w;
            acc[4]+=x1.x; acc[5]+=x1.y; acc[6]+=x1.z; acc[7]+=x1.w;
            acc[8]+=x2.x; acc[9]+=x2.y; acc[10]+=x2.z; acc[11]+=x2.w;
            acc[12]+=x3.x; acc[13]+=x3.y; acc[14]+=x3.z; acc[15]+=x3.w;
        }
    }

    float ss = 0.f;
    #pragma unroll
    for (int k = 0; k < 16; k++) ss += acc[k] * acc[k];
    #pragma unroll
    for (int off = 4; off; off >>= 1) ss += __shfl_xor(ss, off, 8);
    const float inv = 1.0f / fmaxf(sqrtf(ss), 1e-12f);

    {
        ushort8 o0, o1;
        o0[0]=f2bf(acc[0]*inv); o0[1]=f2bf(acc[1]*inv); o0[2]=f2bf(acc[2]*inv); o0[3]=f2bf(acc[3]*inv);
        o0[4]=f2bf(acc[4]*inv); o0[5]=f2bf(acc[5]*inv); o0[6]=f2bf(acc[6]*inv); o0[7]=f2bf(acc[7]*inv);
        o1[0]=f2bf(acc[8]*inv); o1[1]=f2bf(acc[9]*inv); o1[2]=f2bf(acc[10]*inv); o1[3]=f2bf(acc[11]*inv);
        o1[4]=f2bf(acc[12]*inv); o1[5]=f2bf(acc[13]*inv); o1[6]=f2bf(acc[14]*inv); o1[7]=f2bf(acc[15]*inv);
        u16* dst = Al + nl * AST + g * 16;
        *(ushort8*)(dst)     = o0;
        *(ushort8*)(dst + 8) = o1;
    }
    __syncthreads();

    const int w = t >> 6, lane = t & 63;
    const int mb = (w >> 1) * 16, nb = (w & 1) * 64;
    const int quad = lane >> 4, r = lane & 15;
    f32x4 c0 = {0,0,0,0}, c1 = {0,0,0,0}, c2 = {0,0,0,0}, c3 = {0,0,0,0};
    #pragma unroll
    for (int kt = 0; kt < 4; kt++) {
        const int ko = kt * 32 + quad * 8;
        short8 a  = *(const short8*)(Al + (mb + r) * AST + ko);
        short8 b0 = *(const short8*)(Wbf + (nb +  0 + r) * D + ko);
        short8 b1 = *(const short8*)(Wbf + (nb + 16 + r) * D + ko);
        short8 b2 = *(const short8*)(Wbf + (nb + 32 + r) * D + ko);
        short8 b3 = *(const short8*)(Wbf + (nb + 48 + r) * D + ko);
        c0 = __builtin_amdgcn_mfma_f32_16x16x32_bf16(a, b0, c0, 0, 0, 0);
        c1 = __builtin_amdgcn_mfma_f32_16x16x32_bf16(a, b1, c1, 0, 0, 0);
        c2 = __builtin_amdgcn_mfma_f32_16x16x32_bf16(a, b2, c2, 0, 0, 0);
        c3 = __builtin_amdgcn_mfma_f32_16x16x32_bf16(a, b3, c3, 0, 0, 0);
    }

    {
        const float bb0 = bg[nb + r], bb1 = bg[nb + 16 + r];
        const float bb2 = bg[nb + 32 + r], bb3 = bg[nb + 48 + r];
        float* outb = out + (size_t)(nbase + mb + quad * 4) * D;
        #pragma unroll
        for (int reg = 0; reg < 4; reg++) {
            float* rowp = outb + reg * D + nb + r;
            rowp[0]  = c0[reg] + bb0;
            rowp[16] = c1[reg] + bb1;
            rowp[32] = c2[reg] + bb2;
            rowp[48] = c3[reg] + bb3;
        }
    }
}

// ---------- Fallback push path (only if ws tiny) ----------
__global__ __launch_bounds__(256) void scatter(const float* __restrict__ feat,
                                               const int* __restrict__ esrc,
                                               const int* __restrict__ edst,
                                               float* __restrict__ agg) {
    int gid = blockIdx.x * 256 + threadIdx.x;
    int e = gid >> 5;
    int q = (gid & 31) << 2;
    int s = esrc[e];
    int d0 = edst[e];
    const float4 a = *(const float4*)(feat + s * D + q);
    float* dst = agg + d0 * D + q;
    unsafeAtomicAdd(dst + 0, a.x);
    unsafeAtomicAdd(dst + 1, a.y);
    unsafeAtomicAdd(dst + 2, a.z);
    unsafeAtomicAdd(dst + 3, a.w);
}

__global__ __launch_bounds__(256) void norm_linear_mfma(const float* __restrict__ Wg,
                                                        const float* __restrict__ bg,
                                                        float* __restrict__ out) {
    __shared__ u16 Wl[128 * AST];
    __shared__ u16 Al[32 * AST];
    __shared__ float bl[128];
    const int t = threadIdx.x;
    const int nbase = blockIdx.x * 32;

    for (int idx = t * 8; idx < 128 * 128; idx += 256 * 8) {
        int row = idx >> 7, col = idx & 127;
        f32x4 v0 = *(const f32x4*)(Wg + idx);
        f32x4 v1 = *(const f32x4*)(Wg + idx + 4);
        u16* dst = Wl + row * AST + col;
        dst[0] = f2bf(v0.x); dst[1] = f2bf(v0.y); dst[2] = f2bf(v0.z); dst[3] = f2bf(v0.w);
        dst[4] = f2bf(v1.x); dst[5] = f2bf(v1.y); dst[6] = f2bf(v1.z); dst[7] = f2bf(v1.w);
    }
    if (t < 128) bl[t] = bg[t];
    {
        const int n = t >> 3, seg = t & 7;
        const float* src = out + (nbase + n) * D + seg * 16;
        f32x4 v0 = *(const f32x4*)(src);
        f32x4 v1 = *(const f32x4*)(src + 4);
        f32x4 v2 = *(const f32x4*)(src + 8);
        f32x4 v3 = *(const f32x4*)(src + 12);
        float ss = v0.x*v0.x + v0.y*v0.y + v0.z*v0.z + v0.w*v0.w
                 + v1.x*v1.x + v1.y*v1.y + v1.z*v1.z + v1.w*v1.w
                 + v2.x*v2.x + v2.y*v2.y + v2.z*v2.z + v2.w*v2.w
                 + v3.x*v3.x + v3.y*v3.y + v3.z*v3.z + v3.w*v3.w;
        #pragma unroll
        for (int off = 4; off; off >>= 1) ss += __shfl_xor(ss, off, 8);
        const float inv = 1.0f / fmaxf(sqrtf(ss), 1e-12f);
        u16* dst = Al + n * AST + seg * 16;
        dst[0]  = f2bf(v0.x * inv); dst[1]  = f2bf(v0.y * inv);
        dst[2]  = f2bf(v0.z * inv); dst[3]  = f2bf(v0.w * inv);
        dst[4]  = f2bf(v1.x * inv); dst[5]  = f2bf(v1.y * inv);
        dst[6]  = f2bf(v1.z * inv); dst[7]  = f2bf(v1.w * inv);
        dst[8]  = f2bf(v2.x * inv); dst[9]  = f2bf(v2.y * inv);
        dst[10] = f2bf(v2.z * inv); dst[11] = f2bf(v2.w * inv);
        dst[12] = f2bf(v3.x * inv); dst[13] = f2bf(v3.y * inv);
        dst[14] = f2bf(v3.z * inv); dst[15] = f2bf(v3.w * inv);
    }
    __syncthreads();

    const int w = t >> 6, lane = t & 63;
    const int mb = (w >> 1) * 16, nb = (w & 1) * 64;
    const int quad = lane >> 4, r = lane & 15;
    f32x4 c0 = {0,0,0,0}, c1 = {0,0,0,0}, c2 = {0,0,0,0}, c3 = {0,0,0,0};
    #pragma unroll
    for (int kt = 0; kt < 4; kt++) {
        const int ko = kt * 32 + quad * 8;
        short8 a = *(const short8*)(Al + (mb + r) * AST + ko);
        short8 b0 = *(const short8*)(Wl + (nb +  0 + r) * AST + ko);
        short8 b1 = *(const short8*)(Wl + (nb + 16 + r) * AST + ko);
        short8 b2 = *(const short8*)(Wl + (nb + 32 + r) * AST + ko);
        short8 b3 = *(const short8*)(Wl + (nb + 48 + r) * AST + ko);
        c0 = __builtin_amdgcn_mfma_f32_16x16x32_bf16(a, b0, c0, 0, 0, 0);
        c1 = __builtin_amdgcn_mfma_f32_16x16x32_bf16(a, b1, c1, 0, 0, 0);
        c2 = __builtin_amdgcn_mfma_f32_16x16x32_bf16(a, b2, c2, 0, 0, 0);
        c3 = __builtin_amdgcn_mfma_f32_16x16x32_bf16(a, b3, c3, 0, 0, 0);
    }
    {
        float* outb = out + (nbase + mb + quad * 4) * D;
        const float bb0 = bl[nb + r], bb1 = bl[nb + 16 + r];
        const float bb2 = bl[nb + 32 + r], bb3 = bl[nb + 48 + r];
        #pragma unroll
        for (int reg = 0; reg < 4; reg++) {
            float* rowp = outb + reg * D + nb + r;
            rowp[0]  = c0[reg] + bb0;
            rowp[16] = c1[reg] + bb1;
            rowp[32] = c2[reg] + bb2;
            rowp[48] = c3[reg] + bb3;
        }
    }
}

extern "C" void kernel_launch(void* const* d_in, const int* in_sizes, int n_in,
                              void* d_out, int out_size, void* d_ws, size_t ws_size,
                              hipStream_t stream) {
    const float* feat = (const float*)d_in[0];
    const int*   esrc = (const int*)d_in[1];
    const int*   edst = (const int*)d_in[2];
    const float* W = (const float*)d_in[n_in - 2];
    const float* b = (const float*)d_in[n_in - 1];
    float* out = (float*)d_out;

    // ws layout (words): gcnt[3328] | Wbf[8192w] | fine pool[NBINS*BCAP] | featb[6400000w]
    // coarse pool (int2, NCB*CCAP = 2M = 16 MB) lives in d_out, consumed before fused_gnl writes.
    const long poolw = (long)NBINS * BCAP;
    const long need_f32  = 3328 + 8192 + poolw;
    const long need_bf16 = need_f32 + 6400000;
    const long availw = (long)(ws_size / 4);

    if (availw >= need_f32) {
        const bool bf16feat = (availw >= need_bf16);
        int* gcnt = (int*)d_ws;
        u16* Wbf = (u16*)(gcnt + 3328);
        unsigned* pool = (unsigned*)(Wbf + 16384);
        u16* featb = bf16feat ? (u16*)(pool + poolw) : (u16*)nullptr;
        int2* cpool = (int2*)d_out;

        conv_all<<<6271, 256, 0, stream>>>(feat, W, featb, Wbf, gcnt);
        coarse_bin<<<N_EDGES / EPB1, 256, 0, stream>>>(esrc, edst, gcnt, cpool);
        fine_bin<<<NCB * NSLICE, 256, 0, stream>>>(gcnt, cpool, pool);
        if (bf16feat)
            fused_gnl<true><<<NBINS, 256, 0, stream>>>(featb, gcnt, pool, Wbf, b, out);
        else
            fused_gnl<false><<<NBINS, 256, 0, stream>>>(feat, gcnt, pool, Wbf, b, out);
    } else {
        hipMemcpyAsync(out, feat, (size_t)N_NODES * D * sizeof(float),
                       hipMemcpyDeviceToDevice, stream);
        scatter<<<(N_EDGES * 32) / 256, 256, 0, stream>>>(feat, esrc, edst, out);
        norm_linear_mfma<<<N_NODES / 32, 256, 0, stream>>>(W, b, out);
    }
}